// Round 7
// baseline (129.817 us; speedup 1.0000x reference)
//
#include <hip/hip_runtime.h>
#include <stdint.h>

#define BQ 4
#define CC 3
#define MM 4096
#define NN 8192
#define KK 16
#define NP_OFF (BQ*CC*MM*KK)    // coords first, then indices
#define BLOCK 512
#define RPW 8                    // rows per wave (= rows per group)
#define GROUPS 2                 // row groups per block
#define QTS 4                    // point-quarter waves per group
#define ROWS (GROUPS*RPW)        // 16 rows per block
#define CHUNK 1024               // points per LDS buffer (16 KB of float4)
#define NCH (NN/CHUNK)           // 8
#define CST (CHUNK/64)           // 16 wave-steps per chunk
#define QST (CST/QTS)            // 4 steps per quarter-wave
#define EPSD 1e-4f               // dotf-space slack (folded vs reference ~1e-6)

__device__ __forceinline__ float rfl(float x) {
    return __uint_as_float((unsigned)__builtin_amdgcn_readfirstlane((int)__float_as_uint(x)));
}

__global__ __launch_bounds__(BLOCK, 8) void knn_kernel(
    const float* __restrict__ query,
    const float* __restrict__ points,
    float* __restrict__ out)
{
    __shared__ float4 pts[2][CHUNK];        // 32 KB dbuf {x,y,z,-p2/2}
    __shared__ unsigned scratch[ROWS][64];  // 4 KB: taub (floats), then cand
    __shared__ unsigned scnt[ROWS];

    const int tid  = threadIdx.x;
    const int lane = tid & 63;
    const int wv   = tid >> 6;             // 0..7
    const int g    = wv >> 2;              // row group 0..1
    const int qt   = wv & 3;               // point-quarter 0..3
    const int bid  = blockIdx.x;           // 0..1023
    const int b    = bid >> 8;             // batch
    const int rb   = (bid & 255) * ROWS;   // first row of block

    const float* pb = points + b * (CC * NN);
    const float* qb = query  + b * (CC * MM);

    if (tid < ROWS) scnt[tid] = 0;

    // per-row query scalars (wave-uniform -> SGPRs) + exact reference q2
    float qx[RPW], qy[RPW], qz[RPW], q2[RPW], dm[RPW];
    #pragma unroll
    for (int r = 0; r < RPW; ++r) {
        int m = rb + g * RPW + r;
        float x = rfl(qb[m]);
        float y = rfl(qb[MM + m]);
        float z = rfl(qb[2*MM + m]);
        qx[r] = x; qy[r] = y; qz[r] = z;
        q2[r] = rfl(__fadd_rn(__fadd_rn(__fmul_rn(x,x), __fmul_rn(y,y)),
                              __fmul_rn(z,z)));
        dm[r] = -__builtin_inff();         // per-lane MAX of folded dot
    }

    // ---- staging: pack {x,y,z,-0.5*p2}; identical rounding both passes ----
    auto stage = [&](int ch, int bi) {
        #pragma unroll
        for (int i = 0; i < CHUNK / BLOCK; ++i) {   // 2 iters
            int ii = i * BLOCK + tid;
            int n  = ch * CHUNK + ii;
            float px = pb[n], py = pb[NN + n], pz = pb[2*NN + n];
            float p2 = __fadd_rn(__fadd_rn(__fmul_rn(px,px), __fmul_rn(py,py)),
                                 __fmul_rn(pz,pz));
            pts[bi][ii] = make_float4(px, py, pz, -0.5f * p2);
        }
    };

    // ---- Pass 1: per-lane per-row max folded dot over this wave's quarter --
    auto comp1 = [&](int bi) {
        #pragma unroll
        for (int t = 0; t < QST; ++t) {
            float4 P = pts[bi][((qt * QST + t) << 6) + lane];
            #pragma unroll
            for (int r = 0; r < RPW; ++r) {
                float dotf = __builtin_fmaf(qz[r], P.z,
                              __builtin_fmaf(qy[r], P.y,
                               __builtin_fmaf(qx[r], P.x, P.w)));
                dm[r] = fmaxf(dm[r], dotf);
            }
        }
    };

    stage(0, 0);
    #pragma unroll 1
    for (int ch = 0; ch < NCH; ch += 2) {
        __syncthreads();                       // buf0(ch) ready
        if (ch + 1 < NCH) stage(ch + 1, 1);
        comp1(0);
        __syncthreads();                       // buf1 ready; buf0 reads done
        if (ch + 2 < NCH) stage(ch + 2, 0);
        if (ch + 1 < NCH) comp1(1);
    }

    // ---- tau[row] = 16th largest over all 4 quarters' lane-maxes (256 slots,
    //      merged via per-quarter top-16 in LDS). Slot-max argument: tau <=
    //      true 16th-largest dotf AND >=16 points pass the filter. ----
    #pragma unroll
    for (int r = 0; r < RPW; ++r) {
        float v = dm[r];
        #pragma unroll
        for (int k = 2; k <= 64; k <<= 1) {
            #pragma unroll
            for (int j = k >> 1; j > 0; j >>= 1) {
                float o = __shfl_xor(v, j, 64);
                bool keepmin = (((lane & j) == 0) == ((lane & k) == 0));
                v = keepmin ? fminf(v, o) : fmaxf(v, o);
            }
        }
        if (lane >= 48)                         // this quarter's top-16
            scratch[g*RPW + r][qt*16 + lane - 48] = __float_as_uint(v);
    }
    __syncthreads();
    float rc[RPW];
    #pragma unroll
    for (int r = 0; r < RPW; ++r) {
        float v = __uint_as_float(scratch[g*RPW + r][lane]);  // 64 real values
        #pragma unroll
        for (int k = 2; k <= 64; k <<= 1) {
            #pragma unroll
            for (int j = k >> 1; j > 0; j >>= 1) {
                float o = __shfl_xor(v, j, 64);
                bool keepmin = (((lane & j) == 0) == ((lane & k) == 0));
                v = keepmin ? fminf(v, o) : fmaxf(v, o);
            }
        }
        float tau = __shfl(v, 48, 64);          // 16th largest of 64
        rc[r] = rfl(tau - EPSD);
    }

    // ---- Pass 2: recompute folded dot on own quarter, collect candidates --
    // (cand aliases scratch; loop's first barrier orders merge-reads vs writes)
    auto comp2 = [&](int ch, int bi) {
        #pragma unroll
        for (int t = 0; t < QST; ++t) {
            int st = qt * QST + t;
            float4 P = pts[bi][(st << 6) + lane];
            unsigned n = (unsigned)(ch * CHUNK + (st << 6) + lane);
            #pragma unroll
            for (int r = 0; r < RPW; ++r) {
                float dotf = __builtin_fmaf(qz[r], P.z,
                              __builtin_fmaf(qy[r], P.y,
                               __builtin_fmaf(qx[r], P.x, P.w)));
                if (dotf >= rc[r]) {                     // rare (~18/row)
                    unsigned pos = atomicAdd(&scnt[g*RPW + r], 1u);
                    if (pos < 64u) scratch[g*RPW + r][pos] = n;
                }
            }
        }
    };

    stage(0, 0);
    #pragma unroll 1
    for (int ch = 0; ch < NCH; ch += 2) {
        __syncthreads();
        if (ch + 1 < NCH) stage(ch + 1, 1);
        comp2(ch, 0);
        __syncthreads();
        if (ch + 2 < NCH) stage(ch + 2, 0);
        if (ch + 1 < NCH) comp2(ch + 1, 1);
    }
    __syncthreads();

    // ---- Epilogue: wave (g,qt) owns local rows 2qt, 2qt+1 of its group ----
    #pragma unroll
    for (int rr = 0; rr < 2; ++rr) {
        int r   = 2*qt + rr;                 // local row (has q scalars)
        int row = g * RPW + r;
        unsigned c = scnt[row]; if (c > 64u) c = 64u;   // >=16 guaranteed
        unsigned kb = 0xffffffffu, id = 0xffffffffu;
        if (lane < (int)c) {
            id = scratch[row][lane];
            float px = pb[id], py = pb[NN + id], pz = pb[2*NN + id];
            // bit-exact reference rounding (validated R3-R6):
            float p2 = __fadd_rn(__fadd_rn(__fmul_rn(px,px), __fmul_rn(py,py)),
                                 __fmul_rn(pz,pz));
            float dot = __builtin_fmaf(qz[r], pz,
                         __builtin_fmaf(qy[r], py, __fmul_rn(qx[r], px)));
            float d = __fsub_rn(__fadd_rn(q2[r], p2), __fmul_rn(2.0f, dot));
            unsigned fb = __float_as_uint(d);
            kb = (fb & 0x80000000u) ? ~fb : (fb | 0x80000000u);
        }
        #pragma unroll
        for (int k = 2; k <= 64; k <<= 1) {
            #pragma unroll
            for (int j = k >> 1; j > 0; j >>= 1) {
                unsigned ok = __shfl_xor(kb, j, 64);
                unsigned oi = __shfl_xor(id, j, 64);
                bool takeMin  = (((lane & j) == 0) == ((lane & k) == 0));
                bool selfLess = (kb < ok) || (kb == ok && id < oi);
                if (selfLess != takeMin) { kb = ok; id = oi; }
            }
        }
        if (lane < KK) {
            int m  = rb + row;
            int oi = (int)id;
            out[NP_OFF + (b * MM + m) * KK + lane] = (float)oi;
            out[((b * CC + 0) * MM + m) * KK + lane] = pb[oi];
            out[((b * CC + 1) * MM + m) * KK + lane] = pb[NN + oi];
            out[((b * CC + 2) * MM + m) * KK + lane] = pb[2*NN + oi];
        }
    }
}

extern "C" void kernel_launch(void* const* d_in, const int* in_sizes, int n_in,
                              void* d_out, int out_size, void* d_ws, size_t ws_size,
                              hipStream_t stream) {
    // d_in[0] = k (scalar, =16), d_in[1] = query f32 [4,3,4096],
    // d_in[2] = points f32 [4,3,8192]
    const float* query  = (const float*)d_in[1];
    const float* points = (const float*)d_in[2];
    float* out = (float*)d_out;
    dim3 grid(BQ * (MM / ROWS));    // 1024 blocks = 4/CU, 8 waves each
    dim3 block(BLOCK);
    knn_kernel<<<grid, block, 0, stream>>>(query, points, out);
}

// Round 8
// 126.700 us; speedup vs baseline: 1.0246x; 1.0246x over previous
//
#include <hip/hip_runtime.h>
#include <stdint.h>

#define BQ 4
#define CC 3
#define MM 4096
#define NN 8192
#define KK 16
#define NP_OFF (BQ*CC*MM*KK)    // coords first, then indices
#define BLOCK 512
#define RPW 8                    // rows per wave (= rows per group)
#define GROUPS 2                 // row groups per block
#define QTS 4                    // point-quarter waves per group
#define ROWS (GROUPS*RPW)        // 16 rows per block
#define CHUNK 1024               // points per LDS buffer (16 KB of float4)
#define NCH (NN/CHUNK)           // 8
#define CST (CHUNK/64)           // 16 wave-steps per chunk
#define QST (CST/QTS)            // 4 steps per quarter-wave
#define EPSD 1e-4f               // dotf-space slack (folded vs reference ~1e-6)

__device__ __forceinline__ float rfl(float x) {
    return __uint_as_float((unsigned)__builtin_amdgcn_readfirstlane((int)__float_as_uint(x)));
}

__global__ __launch_bounds__(BLOCK, 8) void knn_kernel(
    const float* __restrict__ query,
    const float* __restrict__ points,
    float* __restrict__ out)
{
    __shared__ float4 pts[2][CHUNK];        // 32 KB dbuf {x,y,z,-p2/2}
    __shared__ unsigned scratch[ROWS][64];  // 4 KB: taub (floats), then cand
    __shared__ unsigned scnt[ROWS];

    const int tid  = threadIdx.x;
    const int lane = tid & 63;
    const int wv   = tid >> 6;             // 0..7
    const int g    = wv >> 2;              // row group 0..1
    const int qt   = wv & 3;               // point-quarter 0..3
    const int bid  = blockIdx.x;           // 0..1023
    const int b    = bid >> 8;             // batch
    const int rb   = (bid & 255) * ROWS;   // first row of block

    const float* pb = points + b * (CC * NN);
    const float* qb = query  + b * (CC * MM);

    if (tid < ROWS) scnt[tid] = 0;

    // per-row query scalars (wave-uniform -> SGPRs).
    // ALL accesses to these arrays use compile-time indices (R7 post-mortem:
    // one runtime-indexed access demotes the whole array to scratch).
    float qx[RPW], qy[RPW], qz[RPW], dm[RPW];
    #pragma unroll
    for (int r = 0; r < RPW; ++r) {
        int m = rb + g * RPW + r;
        qx[r] = rfl(qb[m]);
        qy[r] = rfl(qb[MM + m]);
        qz[r] = rfl(qb[2*MM + m]);
        dm[r] = -__builtin_inff();         // per-lane MAX of folded dot
    }

    // ---- staging: pack {x,y,z,-0.5*p2}; identical rounding both passes ----
    auto stage = [&](int ch, int bi) {
        #pragma unroll
        for (int i = 0; i < CHUNK / BLOCK; ++i) {   // 2 iters
            int ii = i * BLOCK + tid;
            int n  = ch * CHUNK + ii;
            float px = pb[n], py = pb[NN + n], pz = pb[2*NN + n];
            float p2 = __fadd_rn(__fadd_rn(__fmul_rn(px,px), __fmul_rn(py,py)),
                                 __fmul_rn(pz,pz));
            pts[bi][ii] = make_float4(px, py, pz, -0.5f * p2);
        }
    };

    // ---- Pass 1: per-lane per-row max folded dot over this wave's quarter --
    auto comp1 = [&](int bi) {
        #pragma unroll
        for (int t = 0; t < QST; ++t) {
            float4 P = pts[bi][((qt * QST + t) << 6) + lane];
            #pragma unroll
            for (int r = 0; r < RPW; ++r) {
                float dotf = __builtin_fmaf(qz[r], P.z,
                              __builtin_fmaf(qy[r], P.y,
                               __builtin_fmaf(qx[r], P.x, P.w)));
                dm[r] = fmaxf(dm[r], dotf);
            }
        }
    };

    stage(0, 0);
    #pragma unroll 1
    for (int ch = 0; ch < NCH; ch += 2) {
        __syncthreads();                       // buf0(ch) ready
        if (ch + 1 < NCH) stage(ch + 1, 1);
        comp1(0);
        __syncthreads();                       // buf1 ready; buf0 reads done
        if (ch + 2 < NCH) stage(ch + 2, 0);
        if (ch + 1 < NCH) comp1(1);
    }

    // ---- tau[row] = 16th largest over all 4 quarters' lane-maxes (256 slots,
    //      merged via per-quarter top-16 in LDS). Slot-max argument: tau <=
    //      true 16th-largest dotf AND >=16 points pass the filter. ----
    #pragma unroll
    for (int r = 0; r < RPW; ++r) {
        float v = dm[r];
        #pragma unroll
        for (int k = 2; k <= 64; k <<= 1) {
            #pragma unroll
            for (int j = k >> 1; j > 0; j >>= 1) {
                float o = __shfl_xor(v, j, 64);
                bool keepmin = (((lane & j) == 0) == ((lane & k) == 0));
                v = keepmin ? fminf(v, o) : fmaxf(v, o);
            }
        }
        if (lane >= 48)                         // this quarter's top-16
            scratch[g*RPW + r][qt*16 + lane - 48] = __float_as_uint(v);
    }
    __syncthreads();
    float rc[RPW];
    #pragma unroll
    for (int r = 0; r < RPW; ++r) {
        float v = __uint_as_float(scratch[g*RPW + r][lane]);  // 64 real values
        #pragma unroll
        for (int k = 2; k <= 64; k <<= 1) {
            #pragma unroll
            for (int j = k >> 1; j > 0; j >>= 1) {
                float o = __shfl_xor(v, j, 64);
                bool keepmin = (((lane & j) == 0) == ((lane & k) == 0));
                v = keepmin ? fminf(v, o) : fmaxf(v, o);
            }
        }
        float tau = __shfl(v, 48, 64);          // 16th largest of 64
        rc[r] = rfl(tau - EPSD);
    }

    // ---- Pass 2: recompute folded dot on own quarter, collect candidates --
    auto comp2 = [&](int ch, int bi) {
        #pragma unroll
        for (int t = 0; t < QST; ++t) {
            int st = qt * QST + t;
            float4 P = pts[bi][(st << 6) + lane];
            unsigned n = (unsigned)(ch * CHUNK + (st << 6) + lane);
            #pragma unroll
            for (int r = 0; r < RPW; ++r) {
                float dotf = __builtin_fmaf(qz[r], P.z,
                              __builtin_fmaf(qy[r], P.y,
                               __builtin_fmaf(qx[r], P.x, P.w)));
                if (dotf >= rc[r]) {                     // rare (~18/row)
                    unsigned pos = atomicAdd(&scnt[g*RPW + r], 1u);
                    if (pos < 64u) scratch[g*RPW + r][pos] = n;
                }
            }
        }
    };

    stage(0, 0);
    #pragma unroll 1
    for (int ch = 0; ch < NCH; ch += 2) {
        __syncthreads();
        if (ch + 1 < NCH) stage(ch + 1, 1);
        comp2(ch, 0);
        __syncthreads();
        if (ch + 2 < NCH) stage(ch + 2, 0);
        if (ch + 1 < NCH) comp2(ch + 1, 1);
    }
    __syncthreads();

    // ---- Epilogue: wave (g,qt) owns rows 2qt, 2qt+1 of its group.
    //      q reloaded from global (L2-hot) -> NO runtime indexing of
    //      register arrays anywhere in the kernel. ----
    #pragma unroll
    for (int rr = 0; rr < 2; ++rr) {
        int row = g * RPW + 2*qt + rr;
        int m   = rb + row;
        float ex = rfl(qb[m]);
        float ey = rfl(qb[MM + m]);
        float ez = rfl(qb[2*MM + m]);
        float eq2 = rfl(__fadd_rn(__fadd_rn(__fmul_rn(ex,ex), __fmul_rn(ey,ey)),
                                  __fmul_rn(ez,ez)));
        unsigned c = scnt[row]; if (c > 64u) c = 64u;   // >=16 guaranteed
        unsigned kb = 0xffffffffu, id = 0xffffffffu;
        if (lane < (int)c) {
            id = scratch[row][lane];
            float px = pb[id], py = pb[NN + id], pz = pb[2*NN + id];
            // bit-exact reference rounding (validated R3-R7):
            float p2 = __fadd_rn(__fadd_rn(__fmul_rn(px,px), __fmul_rn(py,py)),
                                 __fmul_rn(pz,pz));
            float dot = __builtin_fmaf(ez, pz,
                         __builtin_fmaf(ey, py, __fmul_rn(ex, px)));
            float d = __fsub_rn(__fadd_rn(eq2, p2), __fmul_rn(2.0f, dot));
            unsigned fb = __float_as_uint(d);
            kb = (fb & 0x80000000u) ? ~fb : (fb | 0x80000000u);
        }
        #pragma unroll
        for (int k = 2; k <= 64; k <<= 1) {
            #pragma unroll
            for (int j = k >> 1; j > 0; j >>= 1) {
                unsigned ok = __shfl_xor(kb, j, 64);
                unsigned oi = __shfl_xor(id, j, 64);
                bool takeMin  = (((lane & j) == 0) == ((lane & k) == 0));
                bool selfLess = (kb < ok) || (kb == ok && id < oi);
                if (selfLess != takeMin) { kb = ok; id = oi; }
            }
        }
        if (lane < KK) {
            int oi = (int)id;
            out[NP_OFF + (b * MM + m) * KK + lane] = (float)oi;
            out[((b * CC + 0) * MM + m) * KK + lane] = pb[oi];
            out[((b * CC + 1) * MM + m) * KK + lane] = pb[NN + oi];
            out[((b * CC + 2) * MM + m) * KK + lane] = pb[2*NN + oi];
        }
    }
}

extern "C" void kernel_launch(void* const* d_in, const int* in_sizes, int n_in,
                              void* d_out, int out_size, void* d_ws, size_t ws_size,
                              hipStream_t stream) {
    // d_in[0] = k (scalar, =16), d_in[1] = query f32 [4,3,4096],
    // d_in[2] = points f32 [4,3,8192]
    const float* query  = (const float*)d_in[1];
    const float* points = (const float*)d_in[2];
    float* out = (float*)d_out;
    dim3 grid(BQ * (MM / ROWS));    // 1024 blocks = 4/CU, 8 waves each
    dim3 block(BLOCK);
    knn_kernel<<<grid, block, 0, stream>>>(query, points, out);
}

// Round 9
// 105.525 us; speedup vs baseline: 1.2302x; 1.2007x over previous
//
#include <hip/hip_runtime.h>
#include <stdint.h>

#define BQ 4
#define CC 3
#define MM 4096
#define NN 8192
#define KK 16
#define NP_OFF (BQ*CC*MM*KK)    // coords first, then indices
#define BLOCK 512
#define RPW 8                    // rows per wave (= rows per group)
#define GROUPS 2                 // row groups per block
#define QTS 4                    // point-quarter waves per group
#define ROWS (GROUPS*RPW)        // 16 rows per block
#define CHUNK 1024               // points per LDS buffer (16 KB of float4)
#define NCH (NN/CHUNK)           // 8
#define CST (CHUNK/64)           // 16 wave-steps per chunk
#define QST (CST/QTS)            // 4 steps per quarter-wave
#define EPSD 1e-4f               // dotf-space slack (folded vs reference ~1e-6)

__device__ __forceinline__ float rfl(float x) {
    return __uint_as_float((unsigned)__builtin_amdgcn_readfirstlane((int)__float_as_uint(x)));
}
// order-preserving float<->uint maps (monotone increasing)
__device__ __forceinline__ unsigned mapf(float f) {
    unsigned u = __float_as_uint(f);
    return (u & 0x80000000u) ? ~u : (u | 0x80000000u);
}
__device__ __forceinline__ float unmapf(unsigned u) {
    unsigned b = (u & 0x80000000u) ? (u & 0x7fffffffu) : ~u;
    return __uint_as_float(b);
}

__global__ __launch_bounds__(BLOCK, 8) void knn_kernel(
    const float* __restrict__ query,
    const float* __restrict__ points,
    float* __restrict__ out)
{
    __shared__ float4 pts[2][CHUNK];     // 32 KB dbuf {x,y,z,-p2/2}
    __shared__ unsigned aux[ROWS][64];   // 4 KB: slot-max (mapped), then cand
    __shared__ unsigned scnt[ROWS];
    __shared__ unsigned rcbits[ROWS];

    const int tid  = threadIdx.x;
    const int lane = tid & 63;
    const int wv   = tid >> 6;             // 0..7
    const int g    = wv >> 2;              // row group 0..1
    const int qt   = wv & 3;               // point-quarter 0..3
    const int bid  = blockIdx.x;           // 0..1023
    const int b    = bid >> 8;             // batch
    const int rb   = (bid & 255) * ROWS;   // first row of block

    const float* pb = points + b * (CC * NN);
    const float* qb = query  + b * (CC * MM);

    // zero slot-max array (1024 words) + counters
    ((unsigned*)aux)[tid]       = 0u;
    ((unsigned*)aux)[tid + 512] = 0u;
    if (tid < ROWS) scnt[tid] = 0u;

    // per-row query scalars (wave-uniform -> SGPRs); constant indices ONLY
    // (R7 post-mortem: one runtime-indexed access demotes array to scratch).
    float qx[RPW], qy[RPW], qz[RPW], dm[RPW];
    #pragma unroll
    for (int r = 0; r < RPW; ++r) {
        int m = rb + g * RPW + r;
        qx[r] = rfl(qb[m]);
        qy[r] = rfl(qb[MM + m]);
        qz[r] = rfl(qb[2*MM + m]);
        dm[r] = -__builtin_inff();         // per-lane MAX of folded dot
    }

    // ---- staging: pack {x,y,z,-0.5*p2}; identical rounding both passes ----
    auto stage = [&](int ch, int bi) {
        #pragma unroll
        for (int i = 0; i < CHUNK / BLOCK; ++i) {   // 2 iters
            int ii = i * BLOCK + tid;
            int n  = ch * CHUNK + ii;
            float px = pb[n], py = pb[NN + n], pz = pb[2*NN + n];
            float p2 = __fadd_rn(__fadd_rn(__fmul_rn(px,px), __fmul_rn(py,py)),
                                 __fmul_rn(pz,pz));
            pts[bi][ii] = make_float4(px, py, pz, -0.5f * p2);
        }
    };

    // ---- Pass 1: per-lane per-row max folded dot over this wave's quarter --
    auto comp1 = [&](int bi) {
        #pragma unroll
        for (int t = 0; t < QST; ++t) {
            float4 P = pts[bi][((qt * QST + t) << 6) + lane];
            #pragma unroll
            for (int r = 0; r < RPW; ++r) {
                float dotf = __builtin_fmaf(qz[r], P.z,
                              __builtin_fmaf(qy[r], P.y,
                               __builtin_fmaf(qx[r], P.x, P.w)));
                dm[r] = fmaxf(dm[r], dotf);
            }
        }
    };

    stage(0, 0);
    #pragma unroll 1
    for (int ch = 0; ch < NCH; ch += 2) {
        __syncthreads();                       // buf0(ch) ready (also covers init)
        if (ch + 1 < NCH) stage(ch + 1, 1);
        comp1(0);
        __syncthreads();                       // buf1 ready; buf0 reads done
        if (ch + 2 < NCH) stage(ch + 2, 0);
        if (ch + 1 < NCH) comp1(1);
    }

    // ---- selection: slot[s] = max over the 128 points with n%64==s,
    //      via LDS atomicMax of each quarter's lane-max (monotone uint map).
    //      tau = 16th largest of 64 slot-maxes: 16 distinct points >= tau,
    //      and <=15 points exceed d16 => tau <= d16 (same proof as R4-R8). --
    #pragma unroll
    for (int r = 0; r < RPW; ++r)
        atomicMax(&aux[g*RPW + r][lane], mapf(dm[r]));
    __syncthreads();

    // owner wave wv computes rc for rows 2wv, 2wv+1 (16 sorts/block total)
    #pragma unroll
    for (int rr = 0; rr < 2; ++rr) {
        int row = 2*wv + rr;
        unsigned v = aux[row][lane];
        #pragma unroll
        for (int k = 2; k <= 64; k <<= 1) {
            #pragma unroll
            for (int j = k >> 1; j > 0; j >>= 1) {
                unsigned o = __shfl_xor(v, j, 64);
                bool keepmin = (((lane & j) == 0) == ((lane & k) == 0));
                v = keepmin ? (v < o ? v : o) : (v > o ? v : o);
            }
        }
        unsigned tb = __shfl(v, 48, 64);       // 16th largest of 64
        if (lane == 0) rcbits[row] = __float_as_uint(unmapf(tb) - EPSD);
    }
    __syncthreads();                           // rcbits ready; aux reads done

    float rc[RPW];
    #pragma unroll
    for (int r = 0; r < RPW; ++r)
        rc[r] = rfl(__uint_as_float(rcbits[g*RPW + r]));

    // ---- Pass 2: recompute folded dot on own quarter, collect candidates
    //      into aux (safe: slot-max no longer needed after barrier above) ----
    auto comp2 = [&](int ch, int bi) {
        #pragma unroll
        for (int t = 0; t < QST; ++t) {
            int st = qt * QST + t;
            float4 P = pts[bi][(st << 6) + lane];
            unsigned n = (unsigned)(ch * CHUNK + (st << 6) + lane);
            #pragma unroll
            for (int r = 0; r < RPW; ++r) {
                float dotf = __builtin_fmaf(qz[r], P.z,
                              __builtin_fmaf(qy[r], P.y,
                               __builtin_fmaf(qx[r], P.x, P.w)));
                if (dotf >= rc[r]) {                     // rare (~18/row)
                    unsigned pos = atomicAdd(&scnt[g*RPW + r], 1u);
                    if (pos < 64u) aux[g*RPW + r][pos] = n;
                }
            }
        }
    };

    stage(0, 0);
    #pragma unroll 1
    for (int ch = 0; ch < NCH; ch += 2) {
        __syncthreads();
        if (ch + 1 < NCH) stage(ch + 1, 1);
        comp2(ch, 0);
        __syncthreads();
        if (ch + 2 < NCH) stage(ch + 2, 0);
        if (ch + 1 < NCH) comp2(ch + 1, 1);
    }
    __syncthreads();

    // ---- Epilogue: wave wv owns rows 2wv, 2wv+1; q reloaded from global
    //      (L2-hot) so no runtime indexing of register arrays anywhere. ----
    #pragma unroll
    for (int rr = 0; rr < 2; ++rr) {
        int row = 2*wv + rr;
        int m   = rb + row;
        float ex = rfl(qb[m]);
        float ey = rfl(qb[MM + m]);
        float ez = rfl(qb[2*MM + m]);
        float eq2 = rfl(__fadd_rn(__fadd_rn(__fmul_rn(ex,ex), __fmul_rn(ey,ey)),
                                  __fmul_rn(ez,ez)));
        unsigned c = scnt[row]; if (c > 64u) c = 64u;   // >=16 guaranteed
        unsigned kb = 0xffffffffu, id = 0xffffffffu;
        if (lane < (int)c) {
            id = aux[row][lane];
            float px = pb[id], py = pb[NN + id], pz = pb[2*NN + id];
            // bit-exact reference rounding (validated R3-R8):
            float p2 = __fadd_rn(__fadd_rn(__fmul_rn(px,px), __fmul_rn(py,py)),
                                 __fmul_rn(pz,pz));
            float dot = __builtin_fmaf(ez, pz,
                         __builtin_fmaf(ey, py, __fmul_rn(ex, px)));
            float d = __fsub_rn(__fadd_rn(eq2, p2), __fmul_rn(2.0f, dot));
            unsigned fb = __float_as_uint(d);
            kb = (fb & 0x80000000u) ? ~fb : (fb | 0x80000000u);
        }
        #pragma unroll
        for (int k = 2; k <= 64; k <<= 1) {
            #pragma unroll
            for (int j = k >> 1; j > 0; j >>= 1) {
                unsigned ok = __shfl_xor(kb, j, 64);
                unsigned oi = __shfl_xor(id, j, 64);
                bool takeMin  = (((lane & j) == 0) == ((lane & k) == 0));
                bool selfLess = (kb < ok) || (kb == ok && id < oi);
                if (selfLess != takeMin) { kb = ok; id = oi; }
            }
        }
        if (lane < KK) {
            int oi = (int)id;
            out[NP_OFF + (b * MM + m) * KK + lane] = (float)oi;
            out[((b * CC + 0) * MM + m) * KK + lane] = pb[oi];
            out[((b * CC + 1) * MM + m) * KK + lane] = pb[NN + oi];
            out[((b * CC + 2) * MM + m) * KK + lane] = pb[2*NN + oi];
        }
    }
}

extern "C" void kernel_launch(void* const* d_in, const int* in_sizes, int n_in,
                              void* d_out, int out_size, void* d_ws, size_t ws_size,
                              hipStream_t stream) {
    // d_in[0] = k (scalar, =16), d_in[1] = query f32 [4,3,4096],
    // d_in[2] = points f32 [4,3,8192]
    const float* query  = (const float*)d_in[1];
    const float* points = (const float*)d_in[2];
    float* out = (float*)d_out;
    dim3 grid(BQ * (MM / ROWS));    // 1024 blocks = 4/CU, 8 waves each
    dim3 block(BLOCK);
    knn_kernel<<<grid, block, 0, stream>>>(query, points, out);
}